// Round 1
// baseline (12105.038 us; speedup 1.0000x reference)
//
#include <hip/hip_runtime.h>
#include <cstdint>
#include <cstddef>

// Problem constants (B=8, N=2048, M=256)
#define NB 8
#define NN 2048
#define MM 256
#define JBLK 8   // LSTM blocks per batch; each owns 128 of the 1024 gate rows

// ---------------------------------------------------------------------------
// init: zero the per-batch barrier counters (ws is poisoned 0xAA every launch)
// ---------------------------------------------------------------------------
__global__ void init_ctr(unsigned* __restrict__ ctr) {
  ctr[threadIdx.x] = 0u;
}

// ---------------------------------------------------------------------------
// Phase A: LSTM trajectory + fused q projection.
// grid(JBLK, NB), 256 threads. Block (j,b) owns m in [j*32, j*32+32):
// gate rows {g*256 + j*32 + mi} (128 rows) held in VGPRs (128 f32/thread,
// half-row per thread). Per-step h exchange through L2 with an 8-block
// spin barrier (all 64 blocks trivially co-resident on 256 CUs).
// ---------------------------------------------------------------------------
__global__ __launch_bounds__(256, 1) void lstm_q_kernel(
    const float* __restrict__ z_g, const float* __restrict__ dec,
    const float* __restrict__ h0, const float* __restrict__ w_ih,
    const float* __restrict__ w_hh, const float* __restrict__ b_ih,
    const float* __restrict__ b_hh, const float* __restrict__ Wq,
    const float* __restrict__ bq, float* __restrict__ Qout,
    float* __restrict__ Hbuf, unsigned* __restrict__ ctr)
{
  const int j = blockIdx.x;
  const int b = blockIdx.y;
  const int tid = threadIdx.x;

  __shared__ float h_s[MM];
  __shared__ float gate_s[128];
  __shared__ float xb_s[128];

  const int r   = tid >> 1;           // local gate row 0..127
  const int g   = r >> 5;             // gate (i,f,g,o)
  const int mi  = r & 31;
  const int grow = g * 256 + j * 32 + mi;
  const int c0  = (tid & 1) * 128;    // which half of the row this thread owns

  // recurrent weights -> registers (one-time)
  float w[128];
  #pragma unroll
  for (int k = 0; k < 128; ++k) w[k] = w_hh[(size_t)grow * MM + c0 + k];

  // Wq slice -> registers: 32 q-rows per block, 8 threads per row
  const int qr   = tid >> 3;
  const int qc0  = (tid & 7) * 32;
  const int qrow = j * 32 + qr;
  float wq[32];
  #pragma unroll
  for (int k = 0; k < 32; ++k) wq[k] = Wq[(size_t)qrow * MM + qc0 + k];
  const float bqv = bq[qrow];

  // xb = x_proj + b_hh, where x_proj = dec @ w_ih.T + b_ih (constant input)
  {
    float p = 0.f;
    #pragma unroll 8
    for (int k = 0; k < 128; ++k) p += w_ih[(size_t)grow * MM + c0 + k] * dec[c0 + k];
    p += __shfl_xor(p, 1);
    if ((tid & 1) == 0) xb_s[r] = p + b_ih[grow] + b_hh[grow];
  }

  h_s[tid] = h0[tid];
  float c_my = 0.f;
  if (tid < 32) c_my = z_g[b * MM + j * 32 + tid];
  __syncthreads();

  unsigned* ctrb = ctr + b * 64;
  float* hb = Hbuf + (size_t)b * 2 * MM;

  for (int t = 0; t < NN; ++t) {
    // gates = xb + h @ w_hh.T   (h = h^(t) in h_s)
    float acc = 0.f;
    #pragma unroll
    for (int k = 0; k < 128; ++k) acc += w[k] * h_s[c0 + k];
    acc += __shfl_xor(acc, 1);
    if ((tid & 1) == 0) gate_s[r] = xb_s[r] + acc;
    __syncthreads();

    // LSTM cell update for this block's 32 m-values
    if (tid < 32) {
      float ig = gate_s[tid];
      float fg = gate_s[32 + tid];
      float gg = gate_s[64 + tid];
      float og = gate_s[96 + tid];
      ig = 1.f / (1.f + expf(-ig));
      fg = 1.f / (1.f + expf(-fg));
      gg = tanhf(gg);
      og = 1.f / (1.f + expf(-og));
      c_my = fg * c_my + ig * gg;
      float hn = og * tanhf(c_my);
      // agent-scope store -> lands in L2, visible to sibling blocks
      __hip_atomic_store(&hb[((t + 1) & 1) * MM + j * 32 + tid], hn,
                         __ATOMIC_RELAXED, __HIP_MEMORY_SCOPE_AGENT);
    }
    __syncthreads();  // drains vmcnt per wave -> h stores are in L2

    // 8-block barrier for this batch
    if (tid == 0) {
      __hip_atomic_fetch_add(ctrb, 1u, __ATOMIC_RELEASE, __HIP_MEMORY_SCOPE_AGENT);
      const unsigned tgt = (unsigned)(JBLK * (t + 1));
      while (__hip_atomic_load(ctrb, __ATOMIC_ACQUIRE, __HIP_MEMORY_SCOPE_AGENT) < tgt) {
      }
    }
    __syncthreads();

    // reload full h^(t+1) (L1-bypassing agent loads)
    h_s[tid] = __hip_atomic_load(&hb[((t + 1) & 1) * MM + tid],
                                 __ATOMIC_RELAXED, __HIP_MEMORY_SCOPE_AGENT);
    __syncthreads();

    // q_t = Wq @ h^(t+1) + bq  (this block's 32 rows)
    float qa = 0.f;
    #pragma unroll
    for (int k = 0; k < 32; ++k) qa += wq[k] * h_s[qc0 + k];
    qa += __shfl_xor(qa, 1);
    qa += __shfl_xor(qa, 2);
    qa += __shfl_xor(qa, 4);
    if ((tid & 7) == 0)
      Qout[((size_t)b * NN + t) * MM + qrow] = qa + bqv;
  }
}

// ---------------------------------------------------------------------------
// Generic C = A @ B^T (+ col bias). A: [M,K] rows, B: [Ncol,K] rows.
// 64x64 tile, 256 threads, 4x4 micro-tile, K staged in LDS chunks of 32.
// ---------------------------------------------------------------------------
__global__ __launch_bounds__(256, 1) void gemm_nt(
    const float* __restrict__ A, const float* __restrict__ B,
    float* __restrict__ C, const float* __restrict__ bias,
    int M, int Ncol, int K, long sA, long sB, long sC)
{
  __shared__ float As[64][36];
  __shared__ float Bs[64][36];
  const int tx = threadIdx.x & 15;
  const int ty = threadIdx.x >> 4;
  const int row0 = blockIdx.y * 64;
  const int col0 = blockIdx.x * 64;
  const float* Ab = A + (size_t)blockIdx.z * (size_t)sA;
  const float* Bb = B + (size_t)blockIdx.z * (size_t)sB;
  float* Cb = C + (size_t)blockIdx.z * (size_t)sC;

  float acc[4][4];
  #pragma unroll
  for (int i = 0; i < 4; ++i)
    #pragma unroll
    for (int jj = 0; jj < 4; ++jj) acc[i][jj] = 0.f;

  for (int k0 = 0; k0 < K; k0 += 32) {
    #pragma unroll
    for (int it = 0; it < 2; ++it) {
      int f4 = threadIdx.x + it * 256;   // 0..511
      int rr = f4 >> 3;                  // 8 float4 per 32-wide row chunk
      int kq = (f4 & 7) << 2;
      float4 va = *(const float4*)(Ab + (size_t)(row0 + rr) * K + k0 + kq);
      float4 vb = *(const float4*)(Bb + (size_t)(col0 + rr) * K + k0 + kq);
      *(float4*)(&As[rr][kq]) = va;
      *(float4*)(&Bs[rr][kq]) = vb;
    }
    __syncthreads();
    #pragma unroll
    for (int kk = 0; kk < 32; ++kk) {
      float a[4], bv[4];
      #pragma unroll
      for (int i = 0; i < 4; ++i) a[i] = As[ty * 4 + i][kk];
      #pragma unroll
      for (int jj = 0; jj < 4; ++jj) bv[jj] = Bs[tx * 4 + jj][kk];
      #pragma unroll
      for (int i = 0; i < 4; ++i)
        #pragma unroll
        for (int jj = 0; jj < 4; ++jj) acc[i][jj] += a[i] * bv[jj];
    }
    __syncthreads();
  }

  #pragma unroll
  for (int i = 0; i < 4; ++i) {
    float4 o;
    float* op = &o.x;
    #pragma unroll
    for (int jj = 0; jj < 4; ++jj) {
      float v = acc[i][jj];
      if (bias) v += bias[col0 + tx * 4 + jj];
      op[jj] = v;
    }
    *(float4*)(Cb + (size_t)(row0 + ty * 4 + i) * Ncol + col0 + tx * 4) = o;
  }
}

// ---------------------------------------------------------------------------
// Phase D: greedy masked argmax chain. One wave per batch; per-thread 32-bit
// used-mask in a register; butterfly argmax with first-index tie-break
// (matches jnp.argmax); depth-2 row prefetch. Writes sel_step[n] = t.
// Thread element mapping: col = u*256 + lane*4 + jj (u<8, jj<4).
// ---------------------------------------------------------------------------
__global__ __launch_bounds__(64, 1) void select_kernel(
    const float* __restrict__ Sall, int* __restrict__ sel)
{
  const int b = blockIdx.x;
  const int lane = threadIdx.x;
  const float* S = Sall + (size_t)b * NN * NN;
  int* selb = sel + b * NN;
  for (int i = lane; i < NN; i += 64) selb[i] = 0x7fffffff;

  unsigned used = 0u;
  float B0[32], B1[32], B2[32];

  auto loadrow = [&](float (&dst)[32], int t) {
    #pragma unroll
    for (int u = 0; u < 8; ++u) {
      float4 f = *(const float4*)(S + (size_t)t * NN + u * 256 + lane * 4);
      dst[u * 4 + 0] = f.x; dst[u * 4 + 1] = f.y;
      dst[u * 4 + 2] = f.z; dst[u * 4 + 3] = f.w;
    }
  };
  auto step = [&](float (&cur)[32], float (&pf)[32], int t) {
    if (t + 2 < NN) loadrow(pf, t + 2);   // prefetch 2 ahead
    float bv = -3.0e38f;
    int bc = 0x7fffffff;
    #pragma unroll
    for (int u = 0; u < 8; ++u) {
      #pragma unroll
      for (int jj = 0; jj < 4; ++jj) {
        const int bit = u * 4 + jj;
        const int col = u * 256 + lane * 4 + jj;
        const float v = cur[bit];
        const bool ok = !((used >> bit) & 1u);
        if (ok && (v > bv || (v == bv && col < bc))) { bv = v; bc = col; }
      }
    }
    #pragma unroll
    for (int off = 1; off < 64; off <<= 1) {
      float ov = __shfl_xor(bv, off);
      int oc = __shfl_xor(bc, off);
      if (ov > bv || (ov == bv && oc < bc)) { bv = ov; bc = oc; }
    }
    if (((bc >> 2) & 63) == lane) used |= 1u << (((bc >> 8) << 2) | (bc & 3));
    if (lane == 0) selb[bc] = t;
  };

  loadrow(B0, 0);
  loadrow(B1, 1);
  for (int t = 0; t < NN; t += 3) {
    step(B0, B2, t);
    if (t + 1 < NN) step(B1, B0, t + 1);
    if (t + 2 < NN) step(B2, B1, t + 2);
  }
}

// ---------------------------------------------------------------------------
// Phase E: in-place masked softmax per row. Row t masks n iff sel[n] < t;
// masked entries -> exactly 0.0 (matches exp(s-1e9-max) underflow).
// grid(NN, NB), 256 threads.
// ---------------------------------------------------------------------------
__global__ __launch_bounds__(256, 1) void softmax_kernel(
    float* __restrict__ out, const int* __restrict__ sel)
{
  const int t = blockIdx.x;
  const int b = blockIdx.y;
  const int tid = threadIdx.x;
  float* row = out + ((size_t)b * NN + t) * NN;
  const int* selb = sel + b * NN;
  __shared__ float red[8];

  float v[8];
  int sl[8];
  #pragma unroll
  for (int u = 0; u < 2; ++u) {
    float4 f = *(const float4*)(row + u * 1024 + tid * 4);
    int4 s4 = *(const int4*)(selb + u * 1024 + tid * 4);
    v[u * 4 + 0] = f.x; v[u * 4 + 1] = f.y; v[u * 4 + 2] = f.z; v[u * 4 + 3] = f.w;
    sl[u * 4 + 0] = s4.x; sl[u * 4 + 1] = s4.y; sl[u * 4 + 2] = s4.z; sl[u * 4 + 3] = s4.w;
  }

  float mx = -3.0e38f;
  #pragma unroll
  for (int e = 0; e < 8; ++e)
    if (sl[e] >= t) mx = fmaxf(mx, v[e]);
  #pragma unroll
  for (int off = 1; off < 64; off <<= 1) mx = fmaxf(mx, __shfl_xor(mx, off));
  if ((tid & 63) == 0) red[tid >> 6] = mx;
  __syncthreads();
  mx = fmaxf(fmaxf(red[0], red[1]), fmaxf(red[2], red[3]));

  float e8[8];
  float sum = 0.f;
  #pragma unroll
  for (int e = 0; e < 8; ++e) {
    float ex = (sl[e] >= t) ? __expf(v[e] - mx) : 0.f;
    e8[e] = ex;
    sum += ex;
  }
  #pragma unroll
  for (int off = 1; off < 64; off <<= 1) sum += __shfl_xor(sum, off);
  if ((tid & 63) == 0) red[4 + (tid >> 6)] = sum;
  __syncthreads();
  sum = red[4] + red[5] + red[6] + red[7];
  const float inv = 1.f / sum;

  #pragma unroll
  for (int u = 0; u < 2; ++u) {
    float4 o;
    o.x = e8[u * 4 + 0] * inv; o.y = e8[u * 4 + 1] * inv;
    o.z = e8[u * 4 + 2] * inv; o.w = e8[u * 4 + 3] * inv;
    *(float4*)(row + u * 1024 + tid * 4) = o;
  }
}

// ---------------------------------------------------------------------------
// ws layout (floats): keys[4194304] | Q[4194304] | Hbuf[4096] | sel(int)[16384]
//                     | ctr(uint)[512]   -> total ~33.6 MB
// ---------------------------------------------------------------------------
extern "C" void kernel_launch(void* const* d_in, const int* in_sizes, int n_in,
                              void* d_out, int out_size, void* d_ws, size_t ws_size,
                              hipStream_t stream)
{
  (void)in_sizes; (void)n_in; (void)out_size; (void)ws_size;
  const float* emb  = (const float*)d_in[0];
  const float* z_g  = (const float*)d_in[1];
  const float* dec  = (const float*)d_in[2];
  const float* h0   = (const float*)d_in[3];
  const float* w_ih = (const float*)d_in[4];
  const float* w_hh = (const float*)d_in[5];
  const float* b_ih = (const float*)d_in[6];
  const float* b_hh = (const float*)d_in[7];
  const float* Wq   = (const float*)d_in[8];
  const float* bq   = (const float*)d_in[9];
  const float* Wk   = (const float*)d_in[10];
  const float* bk   = (const float*)d_in[11];
  float* out = (float*)d_out;
  float* ws  = (float*)d_ws;

  float*    keys = ws;
  float*    Q    = ws + 4194304;
  float*    Hbuf = ws + 8388608;
  int*      sel  = (int*)(ws + 8392704);
  unsigned* ctr  = (unsigned*)(ws + 8409088);

  init_ctr<<<1, 512, 0, stream>>>(ctr);

  lstm_q_kernel<<<dim3(JBLK, NB), 256, 0, stream>>>(
      z_g, dec, h0, w_ih, w_hh, b_ih, b_hh, Wq, bq, Q, Hbuf, ctr);

  // keys = emb @ Wk.T + bk   ([16384,256] x [256,256]^T)
  gemm_nt<<<dim3(256 / 64, (NB * NN) / 64, 1), 256, 0, stream>>>(
      emb, Wk, keys, bk, NB * NN, 256, 256, 0, 0, 0);

  // S[b] = Q[b] @ keys[b].T  -> straight into d_out
  gemm_nt<<<dim3(NN / 64, NN / 64, NB), 256, 0, stream>>>(
      Q, keys, out, nullptr, NN, NN, 256,
      (long)NN * MM, (long)NN * MM, (long)NN * NN);

  select_kernel<<<NB, 64, 0, stream>>>(out, sel);

  softmax_kernel<<<dim3(NN, NB), 256, 0, stream>>>(out, sel);
}

// Round 2
// 8983.275 us; speedup vs baseline: 1.3475x; 1.3475x over previous
//
#include <hip/hip_runtime.h>
#include <cstdint>
#include <cstddef>

// Problem constants (B=8, N=2048, M=256)
#define NB 8
#define NN 2048
#define MM 256

typedef unsigned long long u64;

// ---------------------------------------------------------------------------
// init: seed the tagged h-exchange buffer with (h0, tag=0)
// ---------------------------------------------------------------------------
__global__ void init_k(const float* __restrict__ h0, u64* __restrict__ Hbuf) {
  const int i = threadIdx.x;  // 256
  const u64 pv = (u64)__float_as_uint(h0[i]);  // tag 0 in high word
  for (int b = 0; b < NB; ++b)
    __hip_atomic_store(&Hbuf[(b * 2 + 0) * MM + i], pv,
                       __ATOMIC_RELAXED, __HIP_MEMORY_SCOPE_AGENT);
}

// ---------------------------------------------------------------------------
// Phase A: LSTM trajectory + fused Q projection.
// grid(8 j-blocks, 8 batches) x 1024 threads (16 waves).
// Block (j,b) owns m in [32j, 32j+32) -> 128 gate rows.
// Thread (w,lane): q = w&7 (k-quarter cols [32q,32q+32)), rg = w>>3,
// lr = rg*64+lane in [0,128), g = lr>>5, mi = lr&31, grow = g*256+32j+mi.
// Each thread holds 32 w_hh floats (8 float4) + 8 Wq floats in VGPRs.
// h exchange: 8-byte atomic (value | step<<32) through the coherence point;
// consumers poll until all 32 tags == t (tag travels with data -> race-free).
// ---------------------------------------------------------------------------
__global__ __launch_bounds__(1024) void lstm_kernel(
    const float* __restrict__ z_g, const float* __restrict__ dec,
    const float* __restrict__ w_ih, const float* __restrict__ w_hh,
    const float* __restrict__ b_ih, const float* __restrict__ b_hh,
    const float* __restrict__ Wq, const float* __restrict__ bq,
    float* __restrict__ Qout, u64* __restrict__ Hbuf)
{
  const int j = blockIdx.x;
  const int b = blockIdx.y;
  const int tid = threadIdx.x;
  const int w = tid >> 6;
  const int lane = tid & 63;
  const int q = w & 7;
  const int rg = w >> 3;
  const int lr = rg * 64 + lane;     // 0..127
  const int g = lr >> 5;             // 0..3
  const int mi = lr & 31;
  const int grow = g * 256 + 32 * j + mi;

  __shared__ __align__(16) float part[128 * 12];   // gate partials [lr][q], pad 12
  __shared__ __align__(16) float part2[32 * 36];   // q partials [mi][q*4+g], pad 36
  __shared__ __align__(16) float h_s[256];
  __shared__ __align__(16) float xb_s[128];

  // --- recurrent weights -> 32 registers (8 float4, constant-indexed) ---
  float wreg[32];
  {
    const float* wr = w_hh + (size_t)grow * MM + 32 * q;
    #pragma unroll
    for (int i = 0; i < 8; ++i) {
      float4 v = *(const float4*)(wr + 4 * i);
      wreg[4 * i + 0] = v.x; wreg[4 * i + 1] = v.y;
      wreg[4 * i + 2] = v.z; wreg[4 * i + 3] = v.w;
    }
  }
  // --- Wq slice: row 32j+mi, cols [32q+8g, 32q+8g+8) ---
  const int qrow = 32 * j + mi;
  const int qcol = 32 * q + 8 * g;
  float4 wq0, wq1;
  {
    const float* wr = Wq + (size_t)qrow * MM + qcol;
    wq0 = *(const float4*)(wr);
    wq1 = *(const float4*)(wr + 4);
  }

  // --- xb = dec@w_ih.T + b_ih + b_hh (constant LSTM input) ---
  {
    float p = 0.f;
    const float* wr = w_ih + (size_t)grow * MM + 32 * q;
    #pragma unroll
    for (int i = 0; i < 8; ++i) {
      float4 wv = *(const float4*)(wr + 4 * i);
      float4 dv = *(const float4*)(dec + 32 * q + 4 * i);
      p += wv.x * dv.x + wv.y * dv.y + wv.z * dv.z + wv.w * dv.w;
    }
    part[lr * 12 + q] = p;
  }
  __syncthreads();
  if (w == 0) {
    #pragma unroll
    for (int rr = 0; rr < 2; ++rr) {
      const int lr2 = lane + rr * 64;
      const int g2 = lr2 >> 5, mi2 = lr2 & 31;
      const int grow2 = g2 * 256 + 32 * j + mi2;
      float4 p0 = *(const float4*)&part[lr2 * 12];
      float4 p1 = *(const float4*)&part[lr2 * 12 + 4];
      xb_s[lr2] = p0.x + p0.y + p0.z + p0.w + p1.x + p1.y + p1.z + p1.w
                + b_ih[grow2] + b_hh[grow2];
    }
  }
  float c_my = 0.f;
  if (w == 0 && lane < 32) c_my = z_g[b * MM + 32 * j + lane];
  __syncthreads();

  u64* hb = Hbuf + (size_t)b * 2 * MM;
  const float bqv = (w == 1 && lane < 32) ? bq[32 * j + lane] : 0.f;

  for (int t = 0; t <= NN; ++t) {
    // ---- phase 1: acquire h^(t) quarter (tagged), matvec partials ----
    u64* hp = hb + (size_t)((t & 1)) * MM + 32 * q + (lane & 31);
    u64 pv = __hip_atomic_load(hp, __ATOMIC_RELAXED, __HIP_MEMORY_SCOPE_AGENT);
    while (!__all((int)((unsigned)(pv >> 32) == (unsigned)t))) {
      __builtin_amdgcn_s_sleep(1);
      pv = __hip_atomic_load(hp, __ATOMIC_RELAXED, __HIP_MEMORY_SCOPE_AGENT);
    }
    const int hvi = (int)(unsigned)pv;

    float acc = 0.f;
    #pragma unroll
    for (int k = 0; k < 32; ++k) {
      const float hk = __uint_as_float((unsigned)__builtin_amdgcn_readlane(hvi, k));
      acc = fmaf(hk, wreg[k], acc);
    }
    part[lr * 12 + q] = acc;
    if (rg == 0 && lane < 32) h_s[q * 32 + lane] = __uint_as_float((unsigned)pv);
    __syncthreads();

    // ---- phase 2a: wave 0 = cell update + publish h^(t+1) ----
    if (w == 0 && lane < 32 && t < NN) {
      const int m = lane;
      float gate[4];
      #pragma unroll
      for (int gg = 0; gg < 4; ++gg) {
        const int row = gg * 32 + m;
        float4 p0 = *(const float4*)&part[row * 12];
        float4 p1 = *(const float4*)&part[row * 12 + 4];
        gate[gg] = xb_s[row] + p0.x + p0.y + p0.z + p0.w
                             + p1.x + p1.y + p1.z + p1.w;
      }
      // sigmoid(x) = 1/(1+e^-x); tanh(x) = 2/(1+e^-2x) - 1
      const float ig = 1.f / (1.f + __expf(-gate[0]));
      const float fg = 1.f / (1.f + __expf(-gate[1]));
      const float gg_ = 2.f / (1.f + __expf(-2.f * gate[2])) - 1.f;
      const float og = 1.f / (1.f + __expf(-gate[3]));
      c_my = fg * c_my + ig * gg_;
      const float hn = og * (2.f / (1.f + __expf(-2.f * c_my)) - 1.f);
      const u64 pk = ((u64)(unsigned)(t + 1) << 32) | (u64)__float_as_uint(hn);
      __hip_atomic_store(&hb[(size_t)((t + 1) & 1) * MM + 32 * j + m], pk,
                         __ATOMIC_RELAXED, __HIP_MEMORY_SCOPE_AGENT);
    }

    // ---- phase 2b: all threads: q-projection partials from h_s = h^(t) ----
    if (t > 0) {
      float4 h0v = *(const float4*)&h_s[qcol];
      float4 h1v = *(const float4*)&h_s[qcol + 4];
      float qa = h0v.x * wq0.x + h0v.y * wq0.y + h0v.z * wq0.z + h0v.w * wq0.w
               + h1v.x * wq1.x + h1v.y * wq1.y + h1v.z * wq1.z + h1v.w * wq1.w;
      part2[mi * 36 + q * 4 + g] = qa;
    }
    __syncthreads();

    // ---- phase 2c: wave 1 reduces q partials -> Q row t-1 ----
    if (t > 0 && w == 1 && lane < 32) {
      float s = 0.f;
      #pragma unroll
      for (int c = 0; c < 8; ++c) {
        float4 p = *(const float4*)&part2[lane * 36 + 4 * c];
        s += p.x + p.y + p.z + p.w;
      }
      Qout[((size_t)b * NN + (t - 1)) * MM + 32 * j + lane] = s + bqv;
    }
  }
}

// ---------------------------------------------------------------------------
// C = A @ B^T (+ col bias). 128x128 tile, 256 threads, 8x8 micro-tile.
// LDS stored k-major (As[kk][row]) so the inner loop is ds_read_b128 only.
// Micro-tile rows {4ty..4ty+3, 64+4ty..}, cols {4tx.., 64+4tx..} keep LDS
// conflicts at the free 2-way level.
// ---------------------------------------------------------------------------
__global__ __launch_bounds__(256) void gemm128(
    const float* __restrict__ A, const float* __restrict__ B,
    float* __restrict__ C, const float* __restrict__ bias,
    int K, int Ncol, long sA, long sB, long sC)
{
  __shared__ __align__(16) float As[32][132];
  __shared__ __align__(16) float Bs[32][132];
  const int tid = threadIdx.x;
  const int tx = tid & 15;
  const int ty = tid >> 4;
  const int row0 = blockIdx.y * 128;
  const int col0 = blockIdx.x * 128;
  const float* Ab = A + (size_t)blockIdx.z * (size_t)sA;
  const float* Bb = B + (size_t)blockIdx.z * (size_t)sB;
  float* Cb = C + (size_t)blockIdx.z * (size_t)sC;

  float acc[8][8];
  #pragma unroll
  for (int i = 0; i < 8; ++i)
    #pragma unroll
    for (int jj = 0; jj < 8; ++jj) acc[i][jj] = 0.f;

  for (int k0 = 0; k0 < K; k0 += 32) {
    #pragma unroll
    for (int it = 0; it < 4; ++it) {
      const int idx = tid + it * 256;       // 0..1023
      const int r = idx >> 3;               // 0..127
      const int c4 = (idx & 7) << 2;        // 0..28
      float4 va = *(const float4*)(Ab + (size_t)(row0 + r) * K + k0 + c4);
      float4 vb = *(const float4*)(Bb + (size_t)(col0 + r) * K + k0 + c4);
      As[c4 + 0][r] = va.x; As[c4 + 1][r] = va.y;
      As[c4 + 2][r] = va.z; As[c4 + 3][r] = va.w;
      Bs[c4 + 0][r] = vb.x; Bs[c4 + 1][r] = vb.y;
      Bs[c4 + 2][r] = vb.z; Bs[c4 + 3][r] = vb.w;
    }
    __syncthreads();
    #pragma unroll
    for (int kk = 0; kk < 32; ++kk) {
      float4 a0 = *(const float4*)&As[kk][ty * 4];
      float4 a1 = *(const float4*)&As[kk][64 + ty * 4];
      float4 b0 = *(const float4*)&Bs[kk][tx * 4];
      float4 b1 = *(const float4*)&Bs[kk][64 + tx * 4];
      const float av[8] = {a0.x, a0.y, a0.z, a0.w, a1.x, a1.y, a1.z, a1.w};
      const float bv[8] = {b0.x, b0.y, b0.z, b0.w, b1.x, b1.y, b1.z, b1.w};
      #pragma unroll
      for (int i = 0; i < 8; ++i)
        #pragma unroll
        for (int jj = 0; jj < 8; ++jj)
          acc[i][jj] = fmaf(av[i], bv[jj], acc[i][jj]);
    }
    __syncthreads();
  }

  #pragma unroll
  for (int i = 0; i < 8; ++i) {
    const int r = row0 + ((i < 4) ? (ty * 4 + i) : (64 + ty * 4 + i - 4));
    float* cp = Cb + (size_t)r * Ncol + col0;
    float4 o0, o1;
    float* o0p = &o0.x; float* o1p = &o1.x;
    #pragma unroll
    for (int jj = 0; jj < 4; ++jj) {
      float v0 = acc[i][jj], v1 = acc[i][jj + 4];
      if (bias) {
        v0 += bias[col0 + tx * 4 + jj];
        v1 += bias[col0 + 64 + tx * 4 + jj];
      }
      o0p[jj] = v0; o1p[jj] = v1;
    }
    *(float4*)(cp + tx * 4) = o0;
    *(float4*)(cp + 64 + tx * 4) = o1;
  }
}

// ---------------------------------------------------------------------------
// Phase D: greedy masked argmax chain. One wave per batch; per-thread 32-bit
// used-mask; butterfly argmax with first-index tie-break; depth-2 prefetch.
// ---------------------------------------------------------------------------
__global__ __launch_bounds__(64, 1) void select_kernel(
    const float* __restrict__ Sall, int* __restrict__ sel)
{
  const int b = blockIdx.x;
  const int lane = threadIdx.x;
  const float* S = Sall + (size_t)b * NN * NN;
  int* selb = sel + b * NN;
  for (int i = lane; i < NN; i += 64) selb[i] = 0x7fffffff;

  unsigned used = 0u;
  float B0[32], B1[32], B2[32];

  auto loadrow = [&](float (&dst)[32], int t) {
    #pragma unroll
    for (int u = 0; u < 8; ++u) {
      float4 f = *(const float4*)(S + (size_t)t * NN + u * 256 + lane * 4);
      dst[u * 4 + 0] = f.x; dst[u * 4 + 1] = f.y;
      dst[u * 4 + 2] = f.z; dst[u * 4 + 3] = f.w;
    }
  };
  auto step = [&](float (&cur)[32], float (&pf)[32], int t) {
    if (t + 2 < NN) loadrow(pf, t + 2);
    float bv = -3.0e38f;
    int bc = 0x7fffffff;
    #pragma unroll
    for (int u = 0; u < 8; ++u) {
      #pragma unroll
      for (int jj = 0; jj < 4; ++jj) {
        const int bit = u * 4 + jj;
        const int col = u * 256 + lane * 4 + jj;
        const float v = cur[bit];
        const bool ok = !((used >> bit) & 1u);
        if (ok && (v > bv || (v == bv && col < bc))) { bv = v; bc = col; }
      }
    }
    #pragma unroll
    for (int off = 1; off < 64; off <<= 1) {
      float ov = __shfl_xor(bv, off);
      int oc = __shfl_xor(bc, off);
      if (ov > bv || (ov == bv && oc < bc)) { bv = ov; bc = oc; }
    }
    if (((bc >> 2) & 63) == lane) used |= 1u << (((bc >> 8) << 2) | (bc & 3));
    if (lane == 0) selb[bc] = t;
  };

  loadrow(B0, 0);
  loadrow(B1, 1);
  for (int t = 0; t < NN; t += 3) {
    step(B0, B2, t);
    if (t + 1 < NN) step(B1, B0, t + 1);
    if (t + 2 < NN) step(B2, B1, t + 2);
  }
}

// ---------------------------------------------------------------------------
// Phase E: in-place masked softmax per row. Row t masks n iff sel[n] < t.
// ---------------------------------------------------------------------------
__global__ __launch_bounds__(256) void softmax_kernel(
    float* __restrict__ out, const int* __restrict__ sel)
{
  const int t = blockIdx.x;
  const int b = blockIdx.y;
  const int tid = threadIdx.x;
  float* row = out + ((size_t)b * NN + t) * NN;
  const int* selb = sel + b * NN;
  __shared__ float red[8];

  float v[8];
  int sl[8];
  #pragma unroll
  for (int u = 0; u < 2; ++u) {
    float4 f = *(const float4*)(row + u * 1024 + tid * 4);
    int4 s4 = *(const int4*)(selb + u * 1024 + tid * 4);
    v[u * 4 + 0] = f.x; v[u * 4 + 1] = f.y; v[u * 4 + 2] = f.z; v[u * 4 + 3] = f.w;
    sl[u * 4 + 0] = s4.x; sl[u * 4 + 1] = s4.y; sl[u * 4 + 2] = s4.z; sl[u * 4 + 3] = s4.w;
  }

  float mx = -3.0e38f;
  #pragma unroll
  for (int e = 0; e < 8; ++e)
    if (sl[e] >= t) mx = fmaxf(mx, v[e]);
  #pragma unroll
  for (int off = 1; off < 64; off <<= 1) mx = fmaxf(mx, __shfl_xor(mx, off));
  if ((tid & 63) == 0) red[tid >> 6] = mx;
  __syncthreads();
  mx = fmaxf(fmaxf(red[0], red[1]), fmaxf(red[2], red[3]));

  float e8[8];
  float sum = 0.f;
  #pragma unroll
  for (int e = 0; e < 8; ++e) {
    float ex = (sl[e] >= t) ? __expf(v[e] - mx) : 0.f;
    e8[e] = ex;
    sum += ex;
  }
  #pragma unroll
  for (int off = 1; off < 64; off <<= 1) sum += __shfl_xor(sum, off);
  if ((tid & 63) == 0) red[4 + (tid >> 6)] = sum;
  __syncthreads();
  sum = red[4] + red[5] + red[6] + red[7];
  const float inv = 1.f / sum;

  #pragma unroll
  for (int u = 0; u < 2; ++u) {
    float4 o;
    o.x = e8[u * 4 + 0] * inv; o.y = e8[u * 4 + 1] * inv;
    o.z = e8[u * 4 + 2] * inv; o.w = e8[u * 4 + 3] * inv;
    *(float4*)(row + u * 1024 + tid * 4) = o;
  }
}

// ---------------------------------------------------------------------------
// ws layout (floats): keys[4194304] | Q[4194304] | Hbuf(u64)[4096] | sel[16384]
// total ~33.7 MB
// ---------------------------------------------------------------------------
extern "C" void kernel_launch(void* const* d_in, const int* in_sizes, int n_in,
                              void* d_out, int out_size, void* d_ws, size_t ws_size,
                              hipStream_t stream)
{
  (void)in_sizes; (void)n_in; (void)out_size; (void)ws_size;
  const float* emb  = (const float*)d_in[0];
  const float* z_g  = (const float*)d_in[1];
  const float* dec  = (const float*)d_in[2];
  const float* h0   = (const float*)d_in[3];
  const float* w_ih = (const float*)d_in[4];
  const float* w_hh = (const float*)d_in[5];
  const float* b_ih = (const float*)d_in[6];
  const float* b_hh = (const float*)d_in[7];
  const float* Wq   = (const float*)d_in[8];
  const float* bq   = (const float*)d_in[9];
  const float* Wk   = (const float*)d_in[10];
  const float* bk   = (const float*)d_in[11];
  float* out = (float*)d_out;
  float* ws  = (float*)d_ws;

  float* keys = ws;
  float* Q    = ws + 4194304;
  u64*   Hbuf = (u64*)(ws + 8388608);   // 4096 u64 = 32 KB
  int*   sel  = (int*)(ws + 8396800);

  init_k<<<1, 256, 0, stream>>>(h0, Hbuf);

  lstm_kernel<<<dim3(8, NB), 1024, 0, stream>>>(
      z_g, dec, w_ih, w_hh, b_ih, b_hh, Wq, bq, Q, Hbuf);

  // keys = emb @ Wk.T + bk  ([16384,256] x [256,256]^T)
  gemm128<<<dim3(MM / 128, (NB * NN) / 128, 1), 256, 0, stream>>>(
      emb, Wk, keys, bk, MM, MM, 0, 0, 0);

  // S[b] = Q[b] @ keys[b].T -> straight into d_out
  gemm128<<<dim3(NN / 128, NN / 128, NB), 256, 0, stream>>>(
      Q, keys, out, nullptr, MM, NN,
      (long)NN * MM, (long)NN * MM, (long)NN * NN);

  select_kernel<<<NB, 64, 0, stream>>>(out, sel);

  softmax_kernel<<<dim3(NN, NB), 256, 0, stream>>>(out, sel);
}